// Round 14
// baseline (122.046 us; speedup 1.0000x reference)
//
#include <hip/hip_runtime.h>

typedef float f32x4 __attribute__((ext_vector_type(4)));
typedef __bf16 bf16x8 __attribute__((ext_vector_type(8)));
typedef unsigned short u16;

__device__ __forceinline__ f32x4 mfma16(bf16x8 a, bf16x8 b, f32x4 c) {
  return __builtin_amdgcn_mfma_f32_16x16x32_bf16(a, b, c, 0, 0, 0);
}

__device__ __forceinline__ void gll16(const void* g, void* l) {
  __builtin_amdgcn_global_load_lds(
      (const __attribute__((address_space(1))) void*)g,
      (__attribute__((address_space(3))) void*)l, 16, 0, 0);
}

// Fragment-linear pack (for Wo / attn-output -> gemm2 operands)
__device__ __forceinline__ int pidx16(int row, int kc) {
  return ((((row >> 6) * 32 + (kc >> 2)) * 4 + ((row >> 4) & 3)) << 6) +
         ((kc & 3) << 4) + (row & 15);
}

// ---------------- f32->bf16: x,Wp row-major; Wo fragment-packed ----------
__global__ void cvt3_kernel(const float* __restrict__ x,
                            const float* __restrict__ wp,
                            const float* __restrict__ wo,
                            __bf16* __restrict__ xb, __bf16* __restrict__ wpb,
                            u16* __restrict__ wox) {
  int idx = blockIdx.x * blockDim.x + threadIdx.x;
  int stride = gridDim.x * blockDim.x;
  for (int i = idx; i < 1048576; i += stride) {
    const float* src;
    int j;
    int mode;
    if (i < 524288) { j = i; src = x + (size_t)j * 8; mode = 0; }
    else if (i < 917504) { j = i - 524288; src = wp + (size_t)j * 8; mode = 1; }
    else { j = i - 917504; src = wo + (size_t)j * 8; mode = 2; }
    f32x4 a = *(const f32x4*)src;
    f32x4 b = *(const f32x4*)(src + 4);
    bf16x8 r;
#pragma unroll
    for (int e = 0; e < 4; ++e) {
      r[e] = (__bf16)a[e];
      r[4 + e] = (__bf16)b[e];
    }
    if (mode == 0) *(bf16x8*)(xb + (size_t)j * 8) = r;
    else if (mode == 1) *(bf16x8*)(wpb + (size_t)j * 8) = r;
    else {
      int row = j >> 7, kc = j & 127;
      *(bf16x8*)(wox + (size_t)pidx16(row, kc) * 8) = r;
    }
  }
}

// ---------------- 8-phase 256x256 bf16 GEMM (m201 port, JIT frag reads) ----
// 512 thr = 8 waves (2M x 4N), wave tile 128x64, BK=64, dbuf slots (128 KB).
// Swizzle: LDS 16B-slot i at row r holds global slot i^(r&7) (pre-swizzled
// gll16 SOURCE, linear LDS dest); reads use slot (ks*4+lg)^(row&7) ->
// conflict-free ds_read_b128.
// Per K-tile 4 phases, quadrants (0,0),(0,1),(1,0),(1,1); fragments read
// just-in-time (max 64 frag VGPRs live). Stage 1 half-tile per phase,
// counted vmcnt(2) once per K-tile (never drains to 0 mid-loop).
// MODE 1: QKV pack epilogue (Q row-major; K/V attn fragment tiles).
template <int MODE>
__global__ __launch_bounds__(512, 2) void gemm8p(
    const u16* __restrict__ A, const u16* __restrict__ B,
    const float* __restrict__ bias, float* __restrict__ Cout,
    __bf16* __restrict__ qb, __bf16* __restrict__ kp, __bf16* __restrict__ vp,
    int N, int K, int mtiles) {
  __shared__ u16 lA[2 * 256 * 64];
  __shared__ u16 lB[2 * 256 * 64];
  const int tid = threadIdx.x;
  const int wid = tid >> 6;
  const int lane = tid & 63;
  const int lr = lane & 15, lg = lane >> 4;

  const int nwg = gridDim.x;
  const int lid = blockIdx.x;
  const int sw = (lid & 7) * (nwg >> 3) + (lid >> 3);
  const int bm = (sw % mtiles) * 256;
  const int bn = (sw / mtiles) * 256;
  const int wm = (wid >> 2) * 128;
  const int wn = (wid & 3) * 64;

  f32x4 acc[8][4] = {};
  const int KT = K >> 6;
  const int NH = KT * 4;

  auto stageh = [&](int h) {
    if (h >= NH) return;
    const int kt = h >> 2, part = h & 3, slot = kt & 1;
    const int kk = kt << 6;
#pragma unroll
    for (int j = 0; j < 2; ++j) {
      int o16 = tid + j * 512;
      int rl = o16 >> 3;                       // row within 128-row half
      int gcol = (((o16 & 7) ^ (rl & 7)) << 3);  // pre-swizzled u16 col
      if (part < 2)
        gll16(A + (size_t)(bm + part * 128 + rl) * K + kk + gcol,
              (char*)lA + slot * 32768 + part * 16384 + o16 * 16);
      else
        gll16(B + (size_t)(bn + (part - 2) * 128 + rl) * K + kk + gcol,
              (char*)lB + slot * 32768 + (part - 2) * 16384 + o16 * 16);
    }
  };

  auto rdA = [&](int slot, int mt, int ks) -> bf16x8 {
    int row = wm + mt * 16 + lr;
    int col = ((ks * 4 + lg) ^ (row & 7)) << 3;
    return *(const bf16x8*)&lA[slot * 16384 + row * 64 + col];
  };
  auto rdB = [&](int slot, int nt, int ks) -> bf16x8 {
    int row = wn + nt * 16 + lr;
    int col = ((ks * 4 + lg) ^ (row & 7)) << 3;
    return *(const bf16x8*)&lB[slot * 16384 + row * 64 + col];
  };

  // prologue: kt0 complete + kt1 ht0; wait leaves only kt1 ht0 in flight
#pragma unroll
  for (int h = 0; h < 5; ++h) stageh(h);
  asm volatile("s_waitcnt vmcnt(2)" ::: "memory");
  __builtin_amdgcn_s_barrier();

  bf16x8 afA[4][2], afB[4][2], bfA[2][2], bfB[2][2];
  for (int kt = 0; kt < KT; ++kt) {
    const int slot = kt & 1;
    const int hb = (kt + 1) * 4;
    // ---------- P0: read afA (8) + bfA (4), quad (0,0) ----------
#pragma unroll
    for (int mt = 0; mt < 4; ++mt) {
      afA[mt][0] = rdA(slot, mt, 0);
      afA[mt][1] = rdA(slot, mt, 1);
    }
#pragma unroll
    for (int nt = 0; nt < 2; ++nt) {
      bfA[nt][0] = rdB(slot, nt, 0);
      bfA[nt][1] = rdB(slot, nt, 1);
    }
    stageh(hb + 1);
    __builtin_amdgcn_sched_barrier(0);
    __builtin_amdgcn_s_barrier();
    asm volatile("s_waitcnt lgkmcnt(0)" ::: "memory");
    __builtin_amdgcn_sched_barrier(0);
    __builtin_amdgcn_s_setprio(1);
#pragma unroll
    for (int mt = 0; mt < 4; ++mt)
#pragma unroll
      for (int nt = 0; nt < 2; ++nt)
#pragma unroll
        for (int ks = 0; ks < 2; ++ks)
          acc[mt][nt] = mfma16(afA[mt][ks], bfA[nt][ks], acc[mt][nt]);
    __builtin_amdgcn_s_setprio(0);
    __builtin_amdgcn_sched_barrier(0);
    __builtin_amdgcn_s_barrier();
    // ---------- P1: read bfB (4), quad (0,1) ----------
#pragma unroll
    for (int nt = 0; nt < 2; ++nt) {
      bfB[nt][0] = rdB(slot, nt + 2, 0);
      bfB[nt][1] = rdB(slot, nt + 2, 1);
    }
    stageh(hb + 2);
    __builtin_amdgcn_sched_barrier(0);
    __builtin_amdgcn_s_barrier();
    asm volatile("s_waitcnt lgkmcnt(0)" ::: "memory");
    __builtin_amdgcn_sched_barrier(0);
    __builtin_amdgcn_s_setprio(1);
#pragma unroll
    for (int mt = 0; mt < 4; ++mt)
#pragma unroll
      for (int nt = 0; nt < 2; ++nt)
#pragma unroll
        for (int ks = 0; ks < 2; ++ks)
          acc[mt][nt + 2] = mfma16(afA[mt][ks], bfB[nt][ks], acc[mt][nt + 2]);
    __builtin_amdgcn_s_setprio(0);
    __builtin_amdgcn_sched_barrier(0);
    __builtin_amdgcn_s_barrier();
    // ---------- P2: read afB (8, replaces afA), quad (1,0) ----------
#pragma unroll
    for (int mt = 0; mt < 4; ++mt) {
      afB[mt][0] = rdA(slot, mt + 4, 0);
      afB[mt][1] = rdA(slot, mt + 4, 1);
    }
    stageh(hb + 3);
    __builtin_amdgcn_sched_barrier(0);
    __builtin_amdgcn_s_barrier();
    asm volatile("s_waitcnt lgkmcnt(0)" ::: "memory");
    __builtin_amdgcn_sched_barrier(0);
    __builtin_amdgcn_s_setprio(1);
#pragma unroll
    for (int mt = 0; mt < 4; ++mt)
#pragma unroll
      for (int nt = 0; nt < 2; ++nt)
#pragma unroll
        for (int ks = 0; ks < 2; ++ks)
          acc[mt + 4][nt] = mfma16(afB[mt][ks], bfA[nt][ks], acc[mt + 4][nt]);
    __builtin_amdgcn_s_setprio(0);
    __builtin_amdgcn_sched_barrier(0);
    __builtin_amdgcn_s_barrier();
    // ---------- P3: no reads, quad (1,1), counted vmcnt ----------
    stageh(hb + 4);
    __builtin_amdgcn_sched_barrier(0);
    __builtin_amdgcn_s_barrier();
    __builtin_amdgcn_s_setprio(1);
#pragma unroll
    for (int mt = 0; mt < 4; ++mt)
#pragma unroll
      for (int nt = 0; nt < 2; ++nt)
#pragma unroll
        for (int ks = 0; ks < 2; ++ks)
          acc[mt + 4][nt + 2] =
              mfma16(afB[mt][ks], bfB[nt][ks], acc[mt + 4][nt + 2]);
    __builtin_amdgcn_s_setprio(0);
    __builtin_amdgcn_sched_barrier(0);
    asm volatile("s_waitcnt vmcnt(2)" ::: "memory");
    __builtin_amdgcn_s_barrier();
  }

  // ---------------- epilogue ----------------
#pragma unroll
  for (int nt = 0; nt < 4; ++nt) {
    int col = bn + wn + nt * 16 + lr;
    float bv = bias[col];
#pragma unroll
    for (int mt = 0; mt < 8; ++mt) {
#pragma unroll
      for (int r = 0; r < 4; ++r) {
        int row = bm + wm + mt * 16 + lg * 4 + r;
        float val = acc[mt][nt][r] + bv;
        if (MODE == 0) {
          Cout[(size_t)row * N + col] = val;
        } else {
          __bf16 bx = (__bf16)val;
          int b = row >> 11, s = row & 2047;
          int third = col >> 10, hd = col & 1023;
          int h = hd >> 6, d = hd & 63;
          if (third == 0) {
            qb[(size_t)row * 1024 + hd] = bx;
          } else {
            int bh = b * 16 + h, t2 = s >> 6, sr = s & 63;
            size_t tb = ((size_t)(bh * 32 + t2)) * 4096;
            if (third == 1)
              kp[tb + (sr >> 4) * 1024 + (d >> 5) * 512 + ((d >> 3) & 3) * 128 +
                 (sr & 15) * 8 + (d & 7)] = bx;
            else
              vp[tb + (d >> 4) * 1024 + (sr >> 5) * 512 + ((sr >> 3) & 3) * 128 +
                 (d & 15) * 8 + (sr & 7)] = bx;
          }
        }
      }
    }
  }
}

// ---------------- barrier-free fragment GEMM (gemm2) ----------------
template <int NREP, int MODE>
__global__ __launch_bounds__(256, 2) void gemm_frag(
    const u16* __restrict__ apx, const u16* __restrict__ bpx,
    const float* __restrict__ bias, float* __restrict__ Cout, int N) {
  const int tid = threadIdx.x;
  const int wid = tid >> 6;
  const int lane = tid & 63;
  const int lr = lane & 15, lg = lane >> 4;

  const int lid = blockIdx.x;
  const int xcd = lid & 7;
  const int local = lid >> 3;
  const int mib = xcd * 2 + (local & 1);
  const int nj = local >> 1;
  const int mi64 = mib * 4 + wid;

  const u16* ab = apx + (size_t)mi64 * 65536 + lane * 8;
  const u16* bb;
  int colbase;
  if (NREP == 4) {
    bb = bpx + (size_t)nj * 65536 + lane * 8;
    colbase = nj * 64;
  } else {
    bb = bpx + (size_t)(nj >> 1) * 65536 + (nj & 1) * 1024 + lane * 8;
    colbase = nj * 32;
  }

  f32x4 acc[4][NREP] = {};
  bf16x8 a0[4], b0[NREP], a1[4], b1[NREP];
#pragma unroll
  for (int mt = 0; mt < 4; ++mt) a0[mt] = *(const bf16x8*)(ab + mt * 512);
#pragma unroll
  for (int nt = 0; nt < NREP; ++nt) b0[nt] = *(const bf16x8*)(bb + nt * 512);

  for (int kt = 0; kt < 32; kt += 2) {
#pragma unroll
    for (int mt = 0; mt < 4; ++mt)
      a1[mt] = *(const bf16x8*)(ab + (kt + 1) * 2048 + mt * 512);
#pragma unroll
    for (int nt = 0; nt < NREP; ++nt)
      b1[nt] = *(const bf16x8*)(bb + (kt + 1) * 2048 + nt * 512);
#pragma unroll
    for (int mt = 0; mt < 4; ++mt)
#pragma unroll
      for (int nt = 0; nt < NREP; ++nt)
        acc[mt][nt] = mfma16(a0[mt], b0[nt], acc[mt][nt]);
    if (kt + 2 < 32) {
#pragma unroll
      for (int mt = 0; mt < 4; ++mt)
        a0[mt] = *(const bf16x8*)(ab + (kt + 2) * 2048 + mt * 512);
#pragma unroll
      for (int nt = 0; nt < NREP; ++nt)
        b0[nt] = *(const bf16x8*)(bb + (kt + 2) * 2048 + nt * 512);
    }
#pragma unroll
    for (int mt = 0; mt < 4; ++mt)
#pragma unroll
      for (int nt = 0; nt < NREP; ++nt)
        acc[mt][nt] = mfma16(a1[mt], b1[nt], acc[mt][nt]);
  }

#pragma unroll
  for (int nt = 0; nt < NREP; ++nt) {
    int col = colbase + nt * 16 + lr;
    float bv = bias[col];
#pragma unroll
    for (int mt = 0; mt < 4; ++mt) {
#pragma unroll
      for (int r = 0; r < 4; ++r) {
        int row = mi64 * 64 + mt * 16 + lg * 4 + r;
        Cout[(size_t)row * N + col] = acc[mt][nt][r] + bv;
      }
    }
  }
}

// ---------------- fused causal+ALiBi flash attention ----------------
__global__ __launch_bounds__(64, 4) void attn_kernel(
    const __bf16* __restrict__ qb, const __bf16* __restrict__ kp,
    const __bf16* __restrict__ vp, u16* __restrict__ abp) {
  __shared__ __bf16 p_lds[16][72];
  const int lane = threadIdx.x & 63;
  const int lr = lane & 15;
  const int lg = lane >> 4;

  const int lid = blockIdx.x;
  const int xcd = lid & 7;
  const int rest = lid >> 3;
  const int bh = xcd * 4 + (rest & 3);
  const int a16 = 127 - (rest >> 2);
  const int b = bh >> 4, h = bh & 15;
  const int qr0 = a16 * 16;
  const int ntl = (a16 >> 2) + 1;

  const float LOG2E = 1.4426950408889634f;
  const float c1 = 0.125f * LOG2E;
  const float c2 = exp2f(-(float)(h + 1) * 0.5f) * LOG2E;

  bf16x8 ones;
#pragma unroll
  for (int j = 0; j < 8; ++j) ones[j] = (__bf16)1.0f;

  const u16* ktiles = (const u16*)kp + (size_t)bh * 32 * 4096;
  const u16* vtiles = (const u16*)vp + (size_t)bh * 32 * 4096;

  const __bf16* qrow = qb + (size_t)(b * 2048 + qr0 + lr) * 1024 + h * 64;
  bf16x8 qf0 = *(const bf16x8*)(qrow + lg * 8);
  bf16x8 qf1 = *(const bf16x8*)(qrow + 32 + lg * 8);

  float m[4], l[4], cq[4];
  f32x4 o[4];
#pragma unroll
  for (int r = 0; r < 4; ++r) {
    m[r] = 0.f;
    l[r] = 0.f;
    cq[r] = c2 * (float)(qr0 + lg * 4 + r);
  }
#pragma unroll
  for (int dt = 0; dt < 4; ++dt) o[dt] = (f32x4){0.f, 0.f, 0.f, 0.f};

  for (int t = 0; t < ntl; ++t) {
    const u16* kb = ktiles + (size_t)t * 4096;
    const u16* vb = vtiles + (size_t)t * 4096;
    const int kv = t * 64;
    const bool last = (t == ntl - 1);

    bf16x8 ka[8], va[8];
#pragma unroll
    for (int j = 0; j < 8; ++j)
      ka[j] = *(const bf16x8*)(kb + j * 512 + lane * 8);
#pragma unroll
    for (int j = 0; j < 8; ++j)
      va[j] = *(const bf16x8*)(vb + j * 512 + lane * 8);

    f32x4 s[4];
#pragma unroll
    for (int nt = 0; nt < 4; ++nt) {
      f32x4 tt = (f32x4){0.f, 0.f, 0.f, 0.f};
      tt = mfma16(qf0, ka[nt * 2], tt);
      tt = mfma16(qf1, ka[nt * 2 + 1], tt);
      s[nt] = tt;
    }

#pragma unroll
    for (int nt = 0; nt < 4; ++nt) {
      float bnt = c2 * (float)(kv + nt * 16 + lr);
#pragma unroll
      for (int r = 0; r < 4; ++r)
        s[nt][r] = __builtin_fmaf(s[nt][r], c1, bnt - cq[r]);
    }
    if (last) {
#pragma unroll
      for (int nt = 0; nt < 4; ++nt) {
        float kf = (float)(kv + nt * 16 + lr);
#pragma unroll
        for (int r = 0; r < 4; ++r) {
          float qi = (float)(qr0 + lg * 4 + r);
          if (kf > qi) s[nt][r] = -1e30f;
        }
      }
    }

    float pm[4];
#pragma unroll
    for (int r = 0; r < 4; ++r)
      pm[r] = fmaxf(fmaxf(s[0][r], s[1][r]), fmaxf(s[2][r], s[3][r]));
    bool ok = (pm[0] <= m[0] + 8.f) && (pm[1] <= m[1] + 8.f) &&
              (pm[2] <= m[2] + 8.f) && (pm[3] <= m[3] + 8.f);
    if (!__all(ok)) {
#pragma unroll
      for (int r = 0; r < 4; ++r)
#pragma unroll
        for (int d = 1; d < 16; d <<= 1)
          pm[r] = fmaxf(pm[r], __shfl_xor(pm[r], d));
#pragma unroll
      for (int r = 0; r < 4; ++r) {
        float mn = fmaxf(m[r], pm[r]);
        float fac = __builtin_amdgcn_exp2f(m[r] - mn);
        m[r] = mn;
        l[r] *= fac;
#pragma unroll
        for (int dt = 0; dt < 4; ++dt) o[dt][r] *= fac;
      }
    }

#pragma unroll
    for (int nt = 0; nt < 4; ++nt)
#pragma unroll
      for (int r = 0; r < 4; ++r) {
        float e = __builtin_amdgcn_exp2f(s[nt][r] - m[r]);
        p_lds[lg * 4 + r][nt * 16 + lr] = (__bf16)e;
      }

    bf16x8 pa0 = *(const bf16x8*)&p_lds[lr][lg * 8];
    bf16x8 pa1 = *(const bf16x8*)&p_lds[lr][32 + lg * 8];

    {
      f32x4 tt = (f32x4){0.f, 0.f, 0.f, 0.f};
      tt = mfma16(pa0, ones, tt);
      tt = mfma16(pa1, ones, tt);
#pragma unroll
      for (int r = 0; r < 4; ++r) l[r] += tt[r];
    }

#pragma unroll
    for (int dt = 0; dt < 4; ++dt) {
      o[dt] = mfma16(pa0, va[dt * 2], o[dt]);
      o[dt] = mfma16(pa1, va[dt * 2 + 1], o[dt]);
    }
  }

  // epilogue: write fragment-packed (gemm2 A-operand)
  const int mi_g = b * 32 + (a16 >> 2);
#pragma unroll
  for (int dt = 0; dt < 4; ++dt)
#pragma unroll
    for (int r = 0; r < 4; ++r) {
      float val = o[dt][r] / l[r];
      __bf16 bx = (__bf16)val;
      int off16 = (((mi_g * 32 + h * 2 + (dt >> 1)) * 4 + (a16 & 3)) << 6) +
                  (((dt & 1) * 2 + (lr >> 3)) << 4) + lg * 4 + r;
      abp[(size_t)off16 * 8 + (lr & 7)] = *(u16*)&bx;
    }
}

extern "C" void kernel_launch(void* const* d_in, const int* in_sizes, int n_in,
                              void* d_out, int out_size, void* d_ws, size_t ws_size,
                              hipStream_t stream) {
  (void)in_sizes; (void)n_in; (void)out_size; (void)ws_size;
  const float* x = (const float*)d_in[0];
  const float* Wp = (const float*)d_in[1];
  const float* bp = (const float*)d_in[2];
  const float* Wo = (const float*)d_in[3];
  const float* bo = (const float*)d_in[4];
  float* out = (float*)d_out;

  char* ws = (char*)d_ws;
  u16* xb  = (u16*)(ws);                        // 8 MB  x bf16 row-major
  u16* wpb = (u16*)(ws + (size_t)(8u << 20));   // 6 MB  Wp bf16 row-major
  u16* wox = (u16*)(ws + (size_t)(14u << 20));  // 2 MB  Wo fragment-packed
  u16* qbp = (u16*)(ws + (size_t)(16u << 20));  // 8 MB  Q row-major
  u16* kpp = (u16*)(ws + (size_t)(24u << 20));  // 8 MB  K fragment tiles
  u16* vpp = (u16*)(ws + (size_t)(32u << 20));  // 8 MB  V fragment tiles
  u16* abp = (u16*)(ws + (size_t)(40u << 20));  // 8 MB  attn out packed

  cvt3_kernel<<<2048, 256, 0, stream>>>(x, Wp, Wo, (__bf16*)xb, (__bf16*)wpb,
                                        wox);
  // gemm1: 8-phase 256x256, grid 16x12 = 192 blocks
  gemm8p<1><<<192, 512, 0, stream>>>(
      xb, wpb, bp, nullptr, (__bf16*)qbp, (__bf16*)kpp, (__bf16*)vpp,
      3072, 1024, 16);
  attn_kernel<<<4096, 64, 0, stream>>>(
      (const __bf16*)qbp, (const __bf16*)kpp, (const __bf16*)vpp, abp);
  // gemm2: fragment GEMM, 16 mib x 32 nj (32-col) = 512 four-wave blocks
  gemm_frag<2, 0><<<512, 256, 0, stream>>>(abp, wox, bo, out, 1024);
}

// Round 15
// 114.855 us; speedup vs baseline: 1.0626x; 1.0626x over previous
//
#include <hip/hip_runtime.h>

typedef float f32x4 __attribute__((ext_vector_type(4)));
typedef __bf16 bf16x8 __attribute__((ext_vector_type(8)));
typedef unsigned short u16;

__device__ __forceinline__ f32x4 mfma16(bf16x8 a, bf16x8 b, f32x4 c) {
  return __builtin_amdgcn_mfma_f32_16x16x32_bf16(a, b, c, 0, 0, 0);
}

__device__ __forceinline__ void gll16(const void* g, void* l) {
  __builtin_amdgcn_global_load_lds(
      (const __attribute__((address_space(1))) void*)g,
      (__attribute__((address_space(3))) void*)l, 16, 0, 0);
}

// ---------------- fused f32 -> bf16 convert (x, Wp, Wo -> contiguous ws) ----
__global__ void cvt3_kernel(const float* __restrict__ x,
                            const float* __restrict__ wp,
                            const float* __restrict__ wo,
                            __bf16* __restrict__ out) {
  int idx = blockIdx.x * blockDim.x + threadIdx.x;
  int stride = gridDim.x * blockDim.x;
  for (int i = idx; i < 1048576; i += stride) {  // 8.39M elems / 8
    const float* src;
    if (i < 524288) src = x + (size_t)i * 8;
    else if (i < 917504) src = wp + (size_t)(i - 524288) * 8;
    else src = wo + (size_t)(i - 917504) * 8;
    f32x4 a = *(const f32x4*)src;
    f32x4 b = *(const f32x4*)(src + 4);
    bf16x8 r;
#pragma unroll
    for (int j = 0; j < 4; ++j) {
      r[j] = (__bf16)a[j];
      r[4 + j] = (__bf16)b[j];
    }
    *(bf16x8*)(out + (size_t)i * 8) = r;
  }
}

// ---------------- gemm1: single-buffer m97-recipe 128x128 ----------------
// 2 __syncthreads per K-step, BK=32, 4 waves 2x2, wave tile 64x64
// (16 MFMA : 8 ds_read_b128 : 4 global_load_lds). (256,2): compiler keeps
// scheduling headroom (measured best gemm1 structure of the session).
// Epilogue: QKV pack — Q row-major; K/V attn fragment-linear tiles.
__global__ __launch_bounds__(256, 2) void gemm1_sb(
    const u16* __restrict__ A, const u16* __restrict__ B,
    const float* __restrict__ bias,
    __bf16* __restrict__ qb, __bf16* __restrict__ kp, __bf16* __restrict__ vp,
    int M, int N, int K, int mtiles) {
  __shared__ u16 lA[128 * 32];
  __shared__ u16 lB[128 * 32];
  const int tid = threadIdx.x;
  const int wid = tid >> 6;
  const int lane = tid & 63;
  const int lr = lane & 15;
  const int lg = lane >> 4;

  // bijective XCD swizzle (gridDim.x % 8 == 0)
  const int nwg = gridDim.x;
  const int lid = blockIdx.x;
  const int sw = (lid & 7) * (nwg >> 3) + (lid >> 3);
  const int bm = (sw % mtiles) * 128;
  const int bn = (sw / mtiles) * 128;
  const int wm = (wid >> 1) * 64;
  const int wn = (wid & 1) * 64;

  f32x4 acc[4][4] = {};

  for (int kt = 0; kt < K; kt += 32) {
    __syncthreads();  // prior reads done before overwrite
#pragma unroll
    for (int j = 0; j < 2; ++j) {
      int beta = tid * 16 + j * 4096;
      int row = beta >> 6;
      int ce = (beta & 63) >> 1;
      gll16(A + (size_t)(bm + row) * K + kt + ce,
            (char*)lA + (wid << 10) + (j << 12));
      gll16(B + (size_t)(bn + row) * K + kt + ce,
            (char*)lB + (wid << 10) + (j << 12));
    }
    __syncthreads();  // staged tile visible (vmcnt drained at barrier)
    bf16x8 af[4], bfr[4];
#pragma unroll
    for (int mt = 0; mt < 4; ++mt)
      af[mt] = *(const bf16x8*)&lA[(wm + mt * 16 + lr) * 32 + lg * 8];
#pragma unroll
    for (int nt = 0; nt < 4; ++nt)
      bfr[nt] = *(const bf16x8*)&lB[(wn + nt * 16 + lr) * 32 + lg * 8];
#pragma unroll
    for (int mt = 0; mt < 4; ++mt)
#pragma unroll
      for (int nt = 0; nt < 4; ++nt)
        acc[mt][nt] = mfma16(af[mt], bfr[nt], acc[mt][nt]);
  }

  // epilogue: Q row-major; K/V fragment-linear packed tiles
#pragma unroll
  for (int nt = 0; nt < 4; ++nt) {
    int col = bn + wn + nt * 16 + lr;
    float bv = bias[col];
#pragma unroll
    for (int mt = 0; mt < 4; ++mt) {
#pragma unroll
      for (int r = 0; r < 4; ++r) {
        int row = bm + wm + mt * 16 + lg * 4 + r;
        float val = acc[mt][nt][r] + bv;
        __bf16 bx = (__bf16)val;
        int b = row >> 11, s = row & 2047;
        int third = col >> 10, hd = col & 1023;
        int h = hd >> 6, d = hd & 63;
        if (third == 0) {
          qb[(size_t)row * 1024 + hd] = bx;
        } else {
          int bh = b * 16 + h, t2 = s >> 6, sr = s & 63;
          size_t tb = ((size_t)(bh * 32 + t2)) * 4096;
          if (third == 1)
            kp[tb + (sr >> 4) * 1024 + (d >> 5) * 512 + ((d >> 3) & 3) * 128 +
               (sr & 15) * 8 + (d & 7)] = bx;
          else
            vp[tb + (d >> 4) * 1024 + (sr >> 5) * 512 + ((sr >> 3) & 3) * 128 +
               (d & 15) * 8 + (sr & 7)] = bx;
        }
      }
    }
  }
}

// ---------------- gemm2: 3-deep counted-vmcnt pipeline + swizzle ----------
// (r11 structure, conflict-free chunk swizzle: LDS chunk16 i holds global
// chunk ((i&3)-(row>>1))&3, read at slot ((lg+(lr>>1))&3).)
template <int BM, int BN>
__global__ __launch_bounds__(256, 3) void gemm_bt(
    const u16* __restrict__ A, const u16* __restrict__ B,
    const float* __restrict__ bias, float* __restrict__ Cout,
    int M, int N, int K, int mtiles) {
  constexpr int MREP = BM / 32;
  constexpr int NREP = BN / 32;
  constexpr int LA = BM / 64;
  constexpr int LB = BN / 64;
  static_assert(LA + LB == 4, "vmcnt literals assume 4 loads/wave/step");
  __shared__ u16 lA[3 * BM * 32];
  __shared__ u16 lB[3 * BN * 32];
  const int tid = threadIdx.x;
  const int wid = tid >> 6;
  const int lane = tid & 63;
  const int lr = lane & 15;
  const int lg = lane >> 4;

  const int nwg = gridDim.x;
  const int lid = blockIdx.x;
  const int sw = (lid & 7) * (nwg >> 3) + (lid >> 3);
  const int bm = (sw % mtiles) * BM;
  const int bn = (sw / mtiles) * BN;
  const int wm = (wid >> 1) * (BM / 2);
  const int wn = (wid & 1) * (BN / 2);

  f32x4 acc[MREP][NREP] = {};

  auto stage = [&](int bf, int t) {
    const int kt = t * 32;
    char* baseA = (char*)lA + bf * (BM * 64);
    char* baseB = (char*)lB + bf * (BN * 64);
#pragma unroll
    for (int j = 0; j < LA; ++j) {
      int i16 = tid + j * 256;
      int row = i16 >> 2;
      int c = ((i16 & 3) - (row >> 1)) & 3;
      gll16(A + (size_t)(bm + row) * K + kt + c * 8, baseA + i16 * 16);
    }
#pragma unroll
    for (int j = 0; j < LB; ++j) {
      int i16 = tid + j * 256;
      int row = i16 >> 2;
      int c = ((i16 & 3) - (row >> 1)) & 3;
      gll16(B + (size_t)(bn + row) * K + kt + c * 8, baseB + i16 * 16);
    }
  };

  const int T = K / 32;
  stage(0, 0);
  stage(1, 1);
  stage(2, 2);

  const int slotA = ((lg + (lr >> 1)) & 3) * 8;

  for (int t = 0; t < T; ++t) {
    const int rem = T - 1 - t;
    if (rem >= 2)
      asm volatile("s_waitcnt vmcnt(8)" ::: "memory");
    else if (rem == 1)
      asm volatile("s_waitcnt vmcnt(4)" ::: "memory");
    else
      asm volatile("s_waitcnt vmcnt(0)" ::: "memory");
    __builtin_amdgcn_s_barrier();

    const u16* cA = lA + (t % 3) * BM * 32;
    const u16* cB = lB + (t % 3) * BN * 32;
    bf16x8 af[MREP], bfr[NREP];
#pragma unroll
    for (int mt = 0; mt < MREP; ++mt)
      af[mt] = *(const bf16x8*)&cA[(wm + mt * 16 + lr) * 32 + slotA];
#pragma unroll
    for (int nt = 0; nt < NREP; ++nt)
      bfr[nt] = *(const bf16x8*)&cB[(wn + nt * 16 + lr) * 32 + slotA];
#pragma unroll
    for (int mt = 0; mt < MREP; ++mt)
#pragma unroll
      for (int nt = 0; nt < NREP; ++nt)
        acc[mt][nt] = mfma16(af[mt], bfr[nt], acc[mt][nt]);

    __builtin_amdgcn_sched_barrier(0);
    __builtin_amdgcn_s_barrier();
    if (t + 3 < T) stage(t % 3, t + 3);
  }

#pragma unroll
  for (int nt = 0; nt < NREP; ++nt) {
    int col = bn + wn + nt * 16 + lr;
    float bv = bias[col];
#pragma unroll
    for (int mt = 0; mt < MREP; ++mt) {
#pragma unroll
      for (int r = 0; r < 4; ++r) {
        int row = bm + wm + mt * 16 + lg * 4 + r;
        Cout[(size_t)row * N + col] = acc[mt][nt][r] + bv;
      }
    }
  }
}

// ---------------- fused causal+ALiBi flash attention ----------------
// 4096 independent 1-wave blocks; K/V fragment-linear packed tiles in L2.
// setprio(1) around MFMA clusters (T5 — measured +4-7% in this regime).
__global__ __launch_bounds__(64, 4) void attn_kernel(
    const __bf16* __restrict__ qb, const __bf16* __restrict__ kp,
    const __bf16* __restrict__ vp, __bf16* __restrict__ aout) {
  __shared__ __bf16 p_lds[16][72];
  const int lane = threadIdx.x & 63;
  const int lr = lane & 15;
  const int lg = lane >> 4;

  const int lid = blockIdx.x;
  const int xcd = lid & 7;
  const int rest = lid >> 3;
  const int bh = xcd * 4 + (rest & 3);
  const int a16 = 127 - (rest >> 2);
  const int b = bh >> 4, h = bh & 15;
  const int qr0 = a16 * 16;
  const int ntl = (a16 >> 2) + 1;

  const float LOG2E = 1.4426950408889634f;
  const float c1 = 0.125f * LOG2E;
  const float c2 = exp2f(-(float)(h + 1) * 0.5f) * LOG2E;

  bf16x8 ones;
#pragma unroll
  for (int j = 0; j < 8; ++j) ones[j] = (__bf16)1.0f;

  const u16* ktiles = (const u16*)kp + (size_t)bh * 32 * 4096;
  const u16* vtiles = (const u16*)vp + (size_t)bh * 32 * 4096;

  const __bf16* qrow = qb + (size_t)(b * 2048 + qr0 + lr) * 1024 + h * 64;
  bf16x8 qf0 = *(const bf16x8*)(qrow + lg * 8);
  bf16x8 qf1 = *(const bf16x8*)(qrow + 32 + lg * 8);

  float m[4], l[4], cq[4];
  f32x4 o[4];
#pragma unroll
  for (int r = 0; r < 4; ++r) {
    m[r] = 0.f;  // defer-max
    l[r] = 0.f;
    cq[r] = c2 * (float)(qr0 + lg * 4 + r);
  }
#pragma unroll
  for (int dt = 0; dt < 4; ++dt) o[dt] = (f32x4){0.f, 0.f, 0.f, 0.f};

  for (int t = 0; t < ntl; ++t) {
    const u16* kb = ktiles + (size_t)t * 4096;
    const u16* vb = vtiles + (size_t)t * 4096;
    const int kv = t * 64;
    const bool last = (t == ntl - 1);

    bf16x8 ka[8], va[8];
#pragma unroll
    for (int j = 0; j < 8; ++j)
      ka[j] = *(const bf16x8*)(kb + j * 512 + lane * 8);
#pragma unroll
    for (int j = 0; j < 8; ++j)
      va[j] = *(const bf16x8*)(vb + j * 512 + lane * 8);

    // ---- QK^T ----
    f32x4 s[4];
    __builtin_amdgcn_s_setprio(1);
#pragma unroll
    for (int nt = 0; nt < 4; ++nt) {
      f32x4 tt = (f32x4){0.f, 0.f, 0.f, 0.f};
      tt = mfma16(qf0, ka[nt * 2], tt);
      tt = mfma16(qf1, ka[nt * 2 + 1], tt);
      s[nt] = tt;
    }
    __builtin_amdgcn_s_setprio(0);

    // ---- logits (log2 domain) ----
#pragma unroll
    for (int nt = 0; nt < 4; ++nt) {
      float bnt = c2 * (float)(kv + nt * 16 + lr);
#pragma unroll
      for (int r = 0; r < 4; ++r)
        s[nt][r] = __builtin_fmaf(s[nt][r], c1, bnt - cq[r]);
    }
    if (last) {
#pragma unroll
      for (int nt = 0; nt < 4; ++nt) {
        float kf = (float)(kv + nt * 16 + lr);
#pragma unroll
        for (int r = 0; r < 4; ++r) {
          float qi = (float)(qr0 + lg * 4 + r);
          if (kf > qi) s[nt][r] = -1e30f;
        }
      }
    }

    // ---- defer-max check ----
    float pm[4];
#pragma unroll
    for (int r = 0; r < 4; ++r)
      pm[r] = fmaxf(fmaxf(s[0][r], s[1][r]), fmaxf(s[2][r], s[3][r]));
    bool ok = (pm[0] <= m[0] + 8.f) && (pm[1] <= m[1] + 8.f) &&
              (pm[2] <= m[2] + 8.f) && (pm[3] <= m[3] + 8.f);
    if (!__all(ok)) {
#pragma unroll
      for (int r = 0; r < 4; ++r)
#pragma unroll
        for (int d = 1; d < 16; d <<= 1)
          pm[r] = fmaxf(pm[r], __shfl_xor(pm[r], d));
#pragma unroll
      for (int r = 0; r < 4; ++r) {
        float mn = fmaxf(m[r], pm[r]);
        float fac = __builtin_amdgcn_exp2f(m[r] - mn);
        m[r] = mn;
        l[r] *= fac;
#pragma unroll
        for (int dt = 0; dt < 4; ++dt) o[dt][r] *= fac;
      }
    }

    // ---- P = exp2(s - m) -> wave-private LDS ----
#pragma unroll
    for (int nt = 0; nt < 4; ++nt)
#pragma unroll
      for (int r = 0; r < 4; ++r) {
        float e = __builtin_amdgcn_exp2f(s[nt][r] - m[r]);
        p_lds[lg * 4 + r][nt * 16 + lr] = (__bf16)e;
      }

    bf16x8 pa0 = *(const bf16x8*)&p_lds[lr][lg * 8];
    bf16x8 pa1 = *(const bf16x8*)&p_lds[lr][32 + lg * 8];

    // ---- row-sum via ones-MFMA + PV ----
    __builtin_amdgcn_s_setprio(1);
    {
      f32x4 tt = (f32x4){0.f, 0.f, 0.f, 0.f};
      tt = mfma16(pa0, ones, tt);
      tt = mfma16(pa1, ones, tt);
#pragma unroll
      for (int r = 0; r < 4; ++r) l[r] += tt[r];
    }
#pragma unroll
    for (int dt = 0; dt < 4; ++dt) {
      o[dt] = mfma16(pa0, va[dt * 2], o[dt]);
      o[dt] = mfma16(pa1, va[dt * 2 + 1], o[dt]);
    }
    __builtin_amdgcn_s_setprio(0);
  }

  // ---- epilogue (row-major bf16) ----
#pragma unroll
  for (int dt = 0; dt < 4; ++dt)
#pragma unroll
    for (int r = 0; r < 4; ++r) {
      float val = o[dt][r] / l[r];
      aout[(size_t)(b * 2048 + qr0 + lg * 4 + r) * 1024 + h * 64 + dt * 16 + lr] =
          (__bf16)val;
    }
}

extern "C" void kernel_launch(void* const* d_in, const int* in_sizes, int n_in,
                              void* d_out, int out_size, void* d_ws, size_t ws_size,
                              hipStream_t stream) {
  (void)in_sizes; (void)n_in; (void)out_size; (void)ws_size;
  const float* x = (const float*)d_in[0];
  const float* Wp = (const float*)d_in[1];
  const float* bp = (const float*)d_in[2];
  const float* Wo = (const float*)d_in[3];
  const float* bo = (const float*)d_in[4];
  float* out = (float*)d_out;

  char* ws = (char*)d_ws;
  u16* xb  = (u16*)(ws);                        // 8 MB  x bf16 row-major
  u16* wpb = (u16*)(ws + (size_t)(8u << 20));   // 6 MB  Wp bf16 row-major
  u16* wob = (u16*)(ws + (size_t)(14u << 20));  // 2 MB  Wo bf16 row-major
  u16* qbp = (u16*)(ws + (size_t)(16u << 20));  // 8 MB  Q row-major
  u16* kpp = (u16*)(ws + (size_t)(24u << 20));  // 8 MB  K fragment tiles
  u16* vpp = (u16*)(ws + (size_t)(32u << 20));  // 8 MB  V fragment tiles
  u16* ab  = xb;  // attention output reuses x_bf16 space

  cvt3_kernel<<<2048, 256, 0, stream>>>(x, Wp, Wo, (__bf16*)xb);
  // gemm1: single-buffer m97-recipe, grid 32*24 = 768 blocks
  gemm1_sb<<<768, 256, 0, stream>>>(
      xb, wpb, bp, (__bf16*)qbp, (__bf16*)kpp, (__bf16*)vpp,
      4096, 3072, 1024, 32);
  attn_kernel<<<4096, 64, 0, stream>>>(
      (const __bf16*)qbp, (const __bf16*)kpp, (const __bf16*)vpp, (__bf16*)ab);
  // gemm2: 3-deep pipelined 128x128, grid 256
  gemm_bt<128, 128><<<256, 256, 0, stream>>>(
      ab, wob, bo, out, 4096, 1024, 1024, 32);
}